// Round 1
// 1346.995 us; speedup vs baseline: 1.5348x; 1.5348x over previous
//
#include <hip/hip_runtime.h>
#include <hip/hip_bf16.h>
#include <stdint.h>

// Problem constants (T, B, N, D) = (4, 16, 1024, 512); M = B*N
#define T_ 4
#define M_ 16384
#define D_ 512
#define R_ (T_ * M_)    // 65536 rows total
#define EPS_TRIG 1e-4f  // ~5 sigma of the bf16-split accumulation noise

typedef short bf16x8 __attribute__((ext_vector_type(8)));   // 8 bf16 (4 VGPRs)
typedef float f32x4  __attribute__((ext_vector_type(4)));

// x = hi + lo + residual, |residual| <= 2^-17 |x|.
// hi: truncation (bit-chop); lo: RNE of the exact fp32 residual.
static __device__ __forceinline__ void split2bf16(float x, unsigned short& h, unsigned short& l) {
    unsigned int u = __float_as_uint(x);
    h = (unsigned short)(u >> 16);
    float r = x - __uint_as_float(u & 0xFFFF0000u);   // exact
    unsigned int v = __float_as_uint(r);
    l = (unsigned short)((v + 0x7FFFu + ((v >> 16) & 1u)) >> 16);
}

// ---------------------------------------------------------------------------
// Kernel 0: one-shot W split -> Wh, Wl in workspace (3 x 512 x 512 each).
// ---------------------------------------------------------------------------
__global__ __launch_bounds__(256) void split_w_kernel(
    const float* __restrict__ Wq, const float* __restrict__ Wk, const float* __restrict__ Wv,
    unsigned short* __restrict__ Wh, unsigned short* __restrict__ Wl)
{
    const int idx4 = blockIdx.x * 256 + threadIdx.x;  // float4 index, < 196608
    const int flat = idx4 * 4;
    const int z    = flat >> 18;                      // 262144 elements per matrix
    const int off  = flat & 262143;
    const float* src = (z == 0) ? Wq : (z == 1) ? Wk : Wv;
    float4 v = *reinterpret_cast<const float4*>(src + off);
    ushort4 h, l;
    split2bf16(v.x, h.x, l.x);
    split2bf16(v.y, h.y, l.y);
    split2bf16(v.z, h.z, l.z);
    split2bf16(v.w, h.w, l.w);
    *reinterpret_cast<ushort4*>(Wh + flat) = h;
    *reinterpret_cast<ushort4*>(Wl + flat) = l;
}

// ---------------------------------------------------------------------------
// Kernel 1: projection via bf16 MFMA (3-term hi/lo split) + LIF + fixup + attn.
//
// Numerics: spike = (mem >= 1.0) vs a float64 reference. Main pass uses
// mfma_f32_16x16x32_bf16 on split operands: xh*wh + xh*wl + xl*wh, noise
// sigma ~2e-5. Chains with any |mem-1| < 1e-4 (5 sigma) are recomputed
// exactly in f64 from the ORIGINAL f32 arrays (round-4-verified fixup).
//
// Verified MFMA layouts (m89/m91/m92): A[m=lane&15][k=(lane>>4)*8+j],
// B^T input with identical addressing (row n = lane&15), C/D col=lane&15,
// row=(lane>>4)*4+reg. Block: 4 waves; tile 32m x 64d; each wave: 16d
// (wsub), 2 m-subtiles, all 3 z and 4 t -> 24 f32x4 accumulators.
// LDS rows padded to 40 bf16 -> b128 frag reads = 8 words/bank (minimum).
// ---------------------------------------------------------------------------
__global__ __launch_bounds__(256) void proj_lif_attn_mfma(
    const float* __restrict__ X,
    const float* __restrict__ Wq, const float* __restrict__ Wk, const float* __restrict__ Wv,
    const unsigned short* __restrict__ WhS, const unsigned short* __restrict__ WlS,
    unsigned char* __restrict__ attn)
{
    __shared__ unsigned short XsH[128 * 40];   // [t*32+m][k]  10 KB
    __shared__ unsigned short XsL[128 * 40];   //              10 KB
    __shared__ unsigned short WsH[192 * 40];   // [z*64+dd][k] 15 KB
    __shared__ unsigned short WsL[192 * 40];   //              15 KB

    const int tid  = threadIdx.x;
    const int lane = tid & 63;
    const int wsub = tid >> 6;     // 0..3 -> 16-d subtile
    const int la   = lane & 15;
    const int lq   = lane >> 4;
    const int bd   = blockIdx.x;   // 0..7   (64 d per block)
    const int bm   = blockIdx.y;   // 0..511 (32 m per block)

    f32x4 acc[2][3][T_];
    #pragma unroll
    for (int s = 0; s < 2; s++)
        #pragma unroll
        for (int z = 0; z < 3; z++)
            #pragma unroll
            for (int t = 0; t < T_; t++)
                acc[s][z][t] = (f32x4){0.f, 0.f, 0.f, 0.f};

    for (int kb = 0; kb < D_; kb += 32) {
        // X stage: 4t x 32m x 32k f32 -> split -> hi/lo bf16 in LDS
        #pragma unroll
        for (int i = 0; i < 4; i++) {
            const int j   = tid + i * 256;  // 0..1023 float4 slots
            const int row = j >> 3;         // 0..127 = t*32+m
            const int kq  = (j & 7) * 4;
            const int t   = row >> 5;
            const int mm  = row & 31;
            float4 xv = *reinterpret_cast<const float4*>(
                X + ((size_t)(t * M_ + bm * 32 + mm) * D_ + kb + kq));
            ushort4 h, l;
            split2bf16(xv.x, h.x, l.x);
            split2bf16(xv.y, h.y, l.y);
            split2bf16(xv.z, h.z, l.z);
            split2bf16(xv.w, h.w, l.w);
            *reinterpret_cast<ushort4*>(&XsH[row * 40 + kq]) = h;
            *reinterpret_cast<ushort4*>(&XsL[row * 40 + kq]) = l;
        }
        // W stage: precomputed bf16 hi/lo, 3z x 64d x 32k each
        {
            const int wd  = tid >> 2;   // 0..63
            const int wkg = tid & 3;    // 0..3 -> k-group of 8
            #pragma unroll
            for (int z = 0; z < 3; z++) {
                const size_t goff = (size_t)(z * D_ + bd * 64 + wd) * D_ + kb + wkg * 8;
                int4 hv = *reinterpret_cast<const int4*>(WhS + goff);
                int4 lv = *reinterpret_cast<const int4*>(WlS + goff);
                *reinterpret_cast<int4*>(&WsH[(z * 64 + wd) * 40 + wkg * 8]) = hv;
                *reinterpret_cast<int4*>(&WsL[(z * 64 + wd) * 40 + wkg * 8]) = lv;
            }
        }
        __syncthreads();

        bf16x8 bh[3], bl[3];
        #pragma unroll
        for (int z = 0; z < 3; z++) {
            const int brow = (z * 64 + wsub * 16 + la) * 40 + lq * 8;
            bh[z] = *reinterpret_cast<const bf16x8*>(&WsH[brow]);
            bl[z] = *reinterpret_cast<const bf16x8*>(&WsL[brow]);
        }
        #pragma unroll
        for (int s = 0; s < 2; s++)
            #pragma unroll
            for (int t = 0; t < T_; t++) {
                const int arow = (t * 32 + s * 16 + la) * 40 + lq * 8;
                bf16x8 ah = *reinterpret_cast<const bf16x8*>(&XsH[arow]);
                bf16x8 al = *reinterpret_cast<const bf16x8*>(&XsL[arow]);
                #pragma unroll
                for (int z = 0; z < 3; z++) {
                    acc[s][z][t] = __builtin_amdgcn_mfma_f32_16x16x32_bf16(ah, bh[z], acc[s][z][t], 0, 0, 0);
                    acc[s][z][t] = __builtin_amdgcn_mfma_f32_16x16x32_bf16(ah, bl[z], acc[s][z][t], 0, 0, 0);
                    acc[s][z][t] = __builtin_amdgcn_mfma_f32_16x16x32_bf16(al, bh[z], acc[s][z][t], 0, 0, 0);
                }
            }
        __syncthreads();
    }

    // Epilogue: LIF (fp32 + exact-f64 fixup) + attn = q * cumsum(k & v)
    const int d = bd * 64 + wsub * 16 + la;
    #pragma unroll
    for (int s = 0; s < 2; s++)
        #pragma unroll
        for (int i = 0; i < 4; i++) {
            const int m = bm * 32 + s * 16 + lq * 4 + i;
            int sp[3][T_];
            #pragma unroll
            for (int z = 0; z < 3; z++) {
                float mem = 0.f;
                bool risky = false;
                #pragma unroll
                for (int t = 0; t < T_; t++) {
                    mem = 0.9f * mem + acc[s][z][t][i];
                    risky |= (fabsf(mem - 1.0f) < EPS_TRIG);
                    const int sb = (mem >= 1.0f) ? 1 : 0;
                    sp[z][t] = sb;
                    mem -= (float)sb;
                }
                if (risky) {
                    const float* Wrow = ((z == 0) ? Wq : ((z == 1) ? Wk : Wv)) + (size_t)d * D_;
                    double pre[T_];
                    #pragma unroll
                    for (int t = 0; t < T_; t++) {
                        const float* xrow = X + (size_t)(t * M_ + m) * D_;
                        double s0 = 0.0, s1 = 0.0, s2 = 0.0, s3 = 0.0;
                        for (int k = 0; k < D_; k += 4) {
                            s0 += (double)xrow[k + 0] * (double)Wrow[k + 0];
                            s1 += (double)xrow[k + 1] * (double)Wrow[k + 1];
                            s2 += (double)xrow[k + 2] * (double)Wrow[k + 2];
                            s3 += (double)xrow[k + 3] * (double)Wrow[k + 3];
                        }
                        pre[t] = (s0 + s1) + (s2 + s3);
                    }
                    double dm = 0.0;
                    #pragma unroll
                    for (int t = 0; t < T_; t++) {
                        dm = 0.9 * dm + pre[t];
                        const int sb = (dm >= 1.0) ? 1 : 0;
                        sp[z][t] = sb;
                        dm -= (double)sb;
                    }
                }
            }
            int ctx = 0;
            #pragma unroll
            for (int t = 0; t < T_; t++) {
                ctx += sp[1][t] & sp[2][t];
                attn[(size_t)(t * M_ + m) * D_ + d] = (unsigned char)(sp[0][t] ? ctx : 0);
            }
        }
}

// ---------------------------------------------------------------------------
// Kernel 2 (NEW): out = attn @ Wp^T + bp via bf16 MFMA.
//
// attn values are exact small integers (0..4) -> exact in bf16. Wp is split
// hi/lo bf16 IN-KERNEL during staging (no extra workspace): out = A*Wh + A*Wl,
// residual |W - (Wh+Wl)| <= 2^-17 |W| -> output noise ~2e-5 against absmax
// tolerance ~2e-3. Accumulation in f32 (MFMA C/D), same as before.
//
// Mirrors kernel 1's VERIFIED layout: A-frag row (s*16+la), k=lq*8;
// B^T-frag row (wsub*16+la), k=lq*8; C/D col=la (->d), row=lq*4+reg (->m).
// Tile: 128 m x 64 d, K-step 32, 4 waves (wsub = 16-d subtile), 8 m-subtiles
// per wave -> 8 f32x4 accumulators. LDS 20.5 KB -> ~7 blocks/CU.
// ---------------------------------------------------------------------------
__global__ __launch_bounds__(256) void attn_out_gemm_mfma(
    const unsigned char* __restrict__ A,    // (R, D) attn, values 0..4
    const float*         __restrict__ Wp,   // (D, D) f32
    const float*         __restrict__ bp,   // (D,)  f32
    float* __restrict__ out)                // (R, D) f32
{
    __shared__ unsigned short As [128 * 40];  // [m][k] bf16, 10 KB
    __shared__ unsigned short Wsh[ 64 * 40];  // [d][k] bf16 hi, 5 KB
    __shared__ unsigned short Wsl[ 64 * 40];  // [d][k] bf16 lo, 5 KB

    const int tid  = threadIdx.x;
    const int lane = tid & 63;
    const int wsub = tid >> 6;     // 0..3 -> 16-d subtile
    const int la   = lane & 15;
    const int lq   = lane >> 4;
    const int bd   = blockIdx.x;   // 0..7   (64 d per block)
    const int bm   = blockIdx.y;   // 0..511 (128 m per block)

    f32x4 acc[8];
    #pragma unroll
    for (int s = 0; s < 8; s++) acc[s] = (f32x4){0.f, 0.f, 0.f, 0.f};

    for (int kb = 0; kb < D_; kb += 32) {
        // A stage: 128 m x 32 k uchar -> bf16 (exact: values 0..4)
        #pragma unroll
        for (int i = 0; i < 4; i++) {
            const int j   = tid + i * 256;  // 0..1023 uchar4 slots
            const int row = j >> 3;         // 0..127
            const int kq  = (j & 7) * 4;
            uchar4 av = *reinterpret_cast<const uchar4*>(
                A + (size_t)(bm * 128 + row) * D_ + kb + kq);
            ushort4 h;
            h.x = (unsigned short)(__float_as_uint((float)av.x) >> 16);
            h.y = (unsigned short)(__float_as_uint((float)av.y) >> 16);
            h.z = (unsigned short)(__float_as_uint((float)av.z) >> 16);
            h.w = (unsigned short)(__float_as_uint((float)av.w) >> 16);
            *reinterpret_cast<ushort4*>(&As[row * 40 + kq]) = h;
        }
        // W stage: 64 d x 32 k f32 -> split hi/lo bf16
        #pragma unroll
        for (int i = 0; i < 2; i++) {
            const int j   = tid + i * 256;  // 0..511 float4 slots
            const int row = j >> 3;         // 0..63
            const int kq  = (j & 7) * 4;
            float4 wv = *reinterpret_cast<const float4*>(
                Wp + (size_t)(bd * 64 + row) * D_ + kb + kq);
            ushort4 h, l;
            split2bf16(wv.x, h.x, l.x);
            split2bf16(wv.y, h.y, l.y);
            split2bf16(wv.z, h.z, l.z);
            split2bf16(wv.w, h.w, l.w);
            *reinterpret_cast<ushort4*>(&Wsh[row * 40 + kq]) = h;
            *reinterpret_cast<ushort4*>(&Wsl[row * 40 + kq]) = l;
        }
        __syncthreads();

        const int brow = (wsub * 16 + la) * 40 + lq * 8;
        bf16x8 bh = *reinterpret_cast<const bf16x8*>(&Wsh[brow]);
        bf16x8 bl = *reinterpret_cast<const bf16x8*>(&Wsl[brow]);
        #pragma unroll
        for (int s = 0; s < 8; s++) {
            bf16x8 a = *reinterpret_cast<const bf16x8*>(&As[(s * 16 + la) * 40 + lq * 8]);
            acc[s] = __builtin_amdgcn_mfma_f32_16x16x32_bf16(a, bh, acc[s], 0, 0, 0);
            acc[s] = __builtin_amdgcn_mfma_f32_16x16x32_bf16(a, bl, acc[s], 0, 0, 0);
        }
        __syncthreads();
    }

    const int d    = bd * 64 + wsub * 16 + la;
    const float bias = bp[d];
    #pragma unroll
    for (int s = 0; s < 8; s++)
        #pragma unroll
        for (int i = 0; i < 4; i++) {
            const int m = bm * 128 + s * 16 + lq * 4 + i;
            out[(size_t)m * D_ + d] = acc[s][i] + bias;
        }
}

extern "C" void kernel_launch(void* const* d_in, const int* in_sizes, int n_in,
                              void* d_out, int out_size, void* d_ws, size_t ws_size,
                              hipStream_t stream) {
    const float* x  = (const float*)d_in[0];  // x_seq (T,B,N,D) f32
    const float* wq = (const float*)d_in[1];
    const float* wk = (const float*)d_in[2];
    const float* wv = (const float*)d_in[3];
    const float* wp = (const float*)d_in[4];
    const float* bp = (const float*)d_in[5];

    // workspace layout: attn 33.5 MB | Wh 1.5 MB | Wl 1.5 MB  (total ~36.7 MB)
    unsigned char*  attn = (unsigned char*)d_ws;
    unsigned short* Wh   = (unsigned short*)((char*)d_ws + 33554432);
    unsigned short* Wl   = (unsigned short*)((char*)d_ws + 33554432 + 1572864);

    dim3 blk(256);
    split_w_kernel<<<dim3(768), blk, 0, stream>>>(wq, wk, wv, Wh, Wl);

    dim3 g1(D_ / 64, M_ / 32);   // (8, 512); bd fastest -> 8 d-blocks share X in L2/L3
    proj_lif_attn_mfma<<<g1, blk, 0, stream>>>(x, wq, wk, wv, Wh, Wl, attn);

    dim3 g2(D_ / 64, R_ / 128);  // (8, 512); bd fastest -> A tile reused across bd in L2
    attn_out_gemm_mfma<<<g2, blk, 0, stream>>>(attn, wp, bp, (float*)d_out);
}